// Round 13
// baseline (66.365 us; speedup 1.0000x reference)
//
#include <hip/hip_runtime.h>

// ---------------------------------------------------------------------------
// out[b,o] = sum_{f,p} x0[b,f]*x[b,p]*W[o,f,p] + bias[o]
//   == GEMM C[4096,256] = A[4096,16384] * W^T,  A[b,f*128+p] = x0[b,f]*x[b,p]
// R13 = R12's barrier-free register-stream K-loop at 2x occupancy. R11/R12
// identical at ~41us gemm -> bound is the shared 8 waves/CU (2/SIMD), not
// staging flavor. Here: grid 1024 (64mb x 4sk x 4ob), 256-thr/4-wave blocks,
// 4 blocks/CU = 16 waves/CU = 4 waves/SIMD (__launch_bounds__(256,4)).
// Wave = 64r x 32o x 2048k: 64 q-major windows (32o x 32k = 2KB, 2 coalesced
// dwordx4 loads), 3-deep named register ring, compiler-scheduled vmcnt, no
// barriers/asm/LDS in loop. Regs: acc 32 + xa 16 + x0v 16 + ring 24 ~= 115
// <= 128 (fits, unlike R8/R9's 192). LDS = 32KB tables only. ob=bid&3 pins
// each XCD to one 2MB L2-resident W slice. Epilogue: split-K-4 f32 atomics
// onto bias-pre-initialized out.
// ---------------------------------------------------------------------------

typedef _Float16 f16x8 __attribute__((ext_vector_type(8)));
typedef float    f32x4 __attribute__((ext_vector_type(4)));

#define WS_WT_OFF  0            // WT3 : 8 MB, per-wave q-major window order
#define WS_XF_OFF  8388608      // Xf  : 1 MB, x f16 seg-XOR
#define WS_X0_OFF  9437184      // X0T2: 1 MB, x0 f16 [mb][row][f] swizzled
#define WS_NEEDED  10485760

__device__ __forceinline__ void gl_lds16(const void* g, void* l) {
  __builtin_amdgcn_global_load_lds(
      (const __attribute__((address_space(1))) void*)g,
      (__attribute__((address_space(3))) void*)l, 16, 0, 0);
}

// ------------------------------ prep kernel --------------------------------
// [0,524288): W f32->f16 into per-wave window-fragment order:
//   from (o,k8): ob=o>>6 oh=(o>>5)&1 n=(o>>4)&1 l=(o&15)|((k8&3)<<4);
//   sk=k8>>9 kh=(k8>>8)&1 fi=(k8>>4)&15 q=(k8>>2)&3;
//   WT3 byte = ((((ob*2+oh)*4+sk)*2+kh)*64 + q*16+fi)*2048 + n*1024 + l*16.
// [524288,589824): x f32->f16 + 16B-seg XOR keyed row&7.
// [589824,655360): x0 f16 [mb][row(64)][f(128)], 16B f-blocks XOR'd row&7.
// [655360,917504): out = bias (float4 groups).
__global__ __launch_bounds__(256) void prep_kernel(
    const float* __restrict__ x0, const float* __restrict__ x,
    const float* __restrict__ W, const float* __restrict__ bias,
    char* __restrict__ WT3, _Float16* __restrict__ Xf,
    _Float16* __restrict__ X0T2, float* __restrict__ out)
{
  int i = blockIdx.x * 256 + threadIdx.x;
  if (i < 524288) {
    int o = i >> 11, k8 = i & 2047;
    const float* s = W + ((size_t)o << 14) + ((size_t)k8 << 3);
    f16x8 h;
#pragma unroll
    for (int e = 0; e < 8; ++e) h[e] = (_Float16)s[e];
    int ob = o >> 6, oh = (o >> 5) & 1, n = (o >> 4) & 1;
    int l  = (o & 15) | ((k8 & 3) << 4);
    int sk = k8 >> 9, kh = (k8 >> 8) & 1, fi = (k8 >> 4) & 15, q = (k8 >> 2) & 3;
    size_t widx = (size_t)((((ob * 2 + oh) * 4 + sk) * 2 + kh) * 64 + q * 16 + fi);
    *(f16x8*)(WT3 + widx * 2048 + n * 1024 + l * 16) = h;
  } else if (i < 589824) {
    int j = i - 524288;
    int r = j >> 4, seg = j & 15;
    const float* s = x + r * 128 + seg * 8;
    f16x8 h;
#pragma unroll
    for (int e = 0; e < 8; ++e) h[e] = (_Float16)s[e];
    int segp = seg ^ (r & 7);
    *(f16x8*)(Xf + r * 128 + segp * 8) = h;
  } else if (i < 655360) {
    int j = i - 589824;                // (mb, row, 8-f block)
    int mb = j >> 10, rem = j & 1023;
    int row = rem >> 4, jb = rem & 15;
    f16x8 h;
#pragma unroll
    for (int e = 0; e < 8; ++e)
      h[e] = (_Float16)x0[(size_t)(mb * 64 + row) * 128 + jb * 8 + e];
    *(f16x8*)(X0T2 + (size_t)mb * 8192 + row * 128 + (jb ^ (row & 7)) * 8) = h;
  } else {
    int j = i - 655360;                // float4 idx into out[4096][256]
    int c = (j * 4) & 255;
    ((float4*)out)[j] = *(const float4*)(bias + c);
  }
}

// ------------------------------ GEMM kernel --------------------------------
__global__ __launch_bounds__(256, 4) void gemm_kernel(
    const char* __restrict__ WT3, const _Float16* __restrict__ Xf,
    const _Float16* __restrict__ X0T2, float* __restrict__ out)
{
  __shared__ __align__(16) char smem[32768];   // [0,16K) x_s; [16K,32K) x0t

  const int bid = blockIdx.x;
  const int mb  = bid >> 4;          // 0..63 : 64-row block
  const int sk  = (bid >> 2) & 3;    // 0..3  : split-K quarter
  const int ob  = bid & 3;           // 0..3  : 64-o block (bid&7 -> XCD slice)

  const int t   = threadIdx.x;
  const int l   = t & 63;
  const int wv  = t >> 6;
  const int oh  = wv & 1;            // o half (32 o)
  const int kh  = wv >> 1;           // k half within sk quarter (2048 k)
  const int lr  = l & 15;
  const int lg  = l >> 4;
  const int swz = lr & 7;
  const int l16 = l * 16;

  const char* wbase = WT3 +
      (size_t)((((ob * 2 + oh) * 4 + sk) * 2 + kh) * 64) * 2048;

  // ---- prologue: x_s + x0t tables -> LDS (one-time) ----
  const char* xsb = (const char*)Xf + (size_t)mb * 16384;
#pragma unroll
  for (int i = 0; i < 4; ++i)
    gl_lds16(xsb + i * 4096 + t * 16, smem + i * 4096 + t * 16);
  const char* x0b = (const char*)X0T2 + (size_t)mb * 16384;
#pragma unroll
  for (int i = 0; i < 4; ++i)
    gl_lds16(x0b + i * 4096 + t * 16, smem + 16384 + i * 4096 + t * 16);
  __syncthreads();

  f32x4 acc[4][2] = {};
  f16x8 xa[4], x0v[4], bw0[2], bw1[2], bw2[2];

#pragma unroll
  for (int m = 0; m < 4; ++m)
    xa[m] = *(const f16x8*)(smem + (m * 16 + lr) * 256 + ((lg ^ swz) << 4));
#pragma unroll
  for (int m = 0; m < 4; ++m)
    x0v[m] = *(const f16x8*)(smem + 16384 + (m * 16 + lr) * 256 +
                             (((sk * 4 + kh * 2) ^ swz) << 4));
  // prime: windows 0,1
#pragma unroll
  for (int i = 0; i < 2; ++i)
    bw0[i] = *(const f16x8*)(wbase + 0 * 2048 + i * 1024 + l16);
#pragma unroll
  for (int i = 0; i < 2; ++i)
    bw1[i] = *(const f16x8*)(wbase + 1 * 2048 + i * 1024 + l16);

  // STEP(WI, BR, BW_, STG): issue window WI+2 -> BW_; boundary xa/x0v
  // reloads (for WI+1); 8 MFMA from BR. No asm, no barriers, no LDS traffic
  // except boundary table reads.
#define STEP(WI, BR, BW_, STG) { \
    if (STG) { \
      _Pragma("unroll") \
      for (int i = 0; i < 2; ++i) \
        BW_[i] = *(const f16x8*)(wbase + ((WI) + 2) * 2048 + i * 1024 + l16); \
    } \
    f16x8 av[4]; \
    _Pragma("unroll") \
    for (int m = 0; m < 4; ++m) \
      av[m] = xa[m] * x0v[m][(WI) & 7]; \
    if ((((WI) + 1) & 15) == 0 && (WI) < 63) { \
      _Pragma("unroll") \
      for (int m = 0; m < 4; ++m) \
        xa[m] = *(const f16x8*)(smem + (m * 16 + lr) * 256 + \
                 ((((((WI) + 1) >> 4) * 4 + lg) ^ swz) << 4)); \
    } \
    if ((((WI) + 1) & 7) == 0 && (WI) < 63) { \
      _Pragma("unroll") \
      for (int m = 0; m < 4; ++m) \
        x0v[m] = *(const f16x8*)(smem + 16384 + (m * 16 + lr) * 256 + \
                  (((sk * 4 + kh * 2 + ((((WI) + 1) >> 3) & 1)) ^ swz) << 4)); \
    } \
    _Pragma("unroll") \
    for (int m = 0; m < 4; ++m) { \
      _Pragma("unroll") \
      for (int n = 0; n < 2; ++n) \
        acc[m][n] = __builtin_amdgcn_mfma_f32_16x16x32_f16( \
            av[m], BR[n], acc[m][n], 0, 0, 0); \
    } \
  }

#define S0(WI, STG) STEP(WI, bw0, bw2, STG)
#define S1(WI, STG) STEP(WI, bw1, bw0, STG)
#define S2(WI, STG) STEP(WI, bw2, bw1, STG)

  S0(0,1)  S1(1,1)  S2(2,1)  S0(3,1)  S1(4,1)  S2(5,1)
  S0(6,1)  S1(7,1)  S2(8,1)  S0(9,1)  S1(10,1) S2(11,1)
  S0(12,1) S1(13,1) S2(14,1) S0(15,1) S1(16,1) S2(17,1)
  S0(18,1) S1(19,1) S2(20,1) S0(21,1) S1(22,1) S2(23,1)
  S0(24,1) S1(25,1) S2(26,1) S0(27,1) S1(28,1) S2(29,1)
  S0(30,1) S1(31,1) S2(32,1) S0(33,1) S1(34,1) S2(35,1)
  S0(36,1) S1(37,1) S2(38,1) S0(39,1) S1(40,1) S2(41,1)
  S0(42,1) S1(43,1) S2(44,1) S0(45,1) S1(46,1) S2(47,1)
  S0(48,1) S1(49,1) S2(50,1) S0(51,1) S1(52,1) S2(53,1)
  S0(54,1) S1(55,1) S2(56,1) S0(57,1) S1(58,1) S2(59,1)
  S0(60,1) S1(61,1) S2(62,0) S0(63,0)

#undef S0
#undef S1
#undef S2
#undef STEP

  // ---- epilogue: split-K-4 accumulate (out pre-initialized to bias) ----
  // C/D layout: col = lane&15, row = (lane>>4)*4 + reg
  float* op = out + (size_t)(mb * 64 + lg * 4) * 256 + ob * 64 + oh * 32 + lr;
#pragma unroll
  for (int m = 0; m < 4; ++m)
#pragma unroll
    for (int n = 0; n < 2; ++n)
#pragma unroll
      for (int rr = 0; rr < 4; ++rr)
        unsafeAtomicAdd(op + (size_t)(m * 16 + rr) * 256 + n * 16,
                        acc[m][n][rr]);
}

// --------------------------- fallback (no ws) ------------------------------
__global__ __launch_bounds__(256) void naive_kernel(
    const float* __restrict__ x0, const float* __restrict__ x,
    const float* __restrict__ W, const float* __restrict__ bias,
    float* __restrict__ out)
{
  __shared__ float x0_s[16][128];
  __shared__ float x_s[16][128];
  const int tid = threadIdx.x;
  const int b0  = blockIdx.x * 16;
  for (int i = tid; i < 16 * 128; i += 256) {
    int bb = i >> 7, c = i & 127;
    x0_s[bb][c] = x0[(size_t)(b0 + bb) * 128 + c];
    x_s[bb][c]  = x[(size_t)(b0 + bb) * 128 + c];
  }
  __syncthreads();
  const int lane = tid & 63, wv = tid >> 6;
  for (int o = wv; o < 256; o += 4) {
    float acc[16];
#pragma unroll
    for (int bb = 0; bb < 16; ++bb) acc[bb] = 0.f;
    for (int it = 0; it < 256; ++it) {
      int k = it * 64 + lane;
      float wval = W[(size_t)o * 16384 + k];
      int f = k >> 7, p = k & 127;
#pragma unroll
      for (int bb = 0; bb < 16; ++bb)
        acc[bb] += wval * (x0_s[bb][f] * x_s[bb][p]);
    }
#pragma unroll
    for (int bb = 0; bb < 16; ++bb) {
      float v = acc[bb];
      for (int off = 32; off; off >>= 1) v += __shfl_down(v, off);
      if (lane == 0) out[(size_t)(b0 + bb) * 256 + o] = v + bias[o];
    }
  }
}

// ------------------------------- launcher ----------------------------------
extern "C" void kernel_launch(void* const* d_in, const int* in_sizes, int n_in,
                              void* d_out, int out_size, void* d_ws,
                              size_t ws_size, hipStream_t stream)
{
  const float* x0   = (const float*)d_in[0];
  const float* x    = (const float*)d_in[1];
  const float* W    = (const float*)d_in[2];
  const float* bias = (const float*)d_in[3];
  float* out = (float*)d_out;

  if (ws_size >= (size_t)WS_NEEDED) {
    char*     WT3  = (char*)d_ws + WS_WT_OFF;
    _Float16* Xf   = (_Float16*)((char*)d_ws + WS_XF_OFF);
    _Float16* X0T2 = (_Float16*)((char*)d_ws + WS_X0_OFF);
    prep_kernel<<<3584, 256, 0, stream>>>(x0, x, W, bias, WT3, Xf, X0T2, out);
    gemm_kernel<<<1024, 256, 0, stream>>>(WT3, Xf, X0T2, out);
  } else {
    naive_kernel<<<256, 256, 0, stream>>>(x0, x, W, bias, out);
  }
}

// Round 14
// 63.687 us; speedup vs baseline: 1.0420x; 1.0420x over previous
//
#include <hip/hip_runtime.h>

// ---------------------------------------------------------------------------
// out[b,o] = sum_{f,p} x0[b,f]*x[b,p]*W[o,f,p] + bias[o]
//   == GEMM C[4096,256] = A[4096,16384] * W^T,  A[b,f*128+p] = x0[b,f]*x[b,p]
// R14 = R12's barrier-free register-stream K-loop with BM=128 (W-traffic /2
// + intra-CU L1 reuse). R13 refuted the occupancy theory (occ up, perf down,
// state demoted at VGPR=60). R12's remaining audited cost: W re-read 64x ->
// 512 MB L2 / 2 MB per-CU L1-ingest with zero reuse. Here: 512 thr / 8 waves
// (2m x 4n); m-paired waves read the SAME 4KB W window (L1 hit for the
// second); W traffic 256 MB, ingest 1 MB/CU. Per-wave structure unchanged
// from R12 (64 q-major windows of 64o x 32k, 4 coalesced dwordx4 each,
// 3-deep named register ring, compiler-scheduled vmcnt, no barriers/asm/LDS
// in loop; regs ~110 <= 128 cap, R11-proven). Grid 256 = 32 mb x 8 sk;
// sk=bid&7 -> per-XCD 1MB L2-resident W k-slice. Split-K-8 via f32 atomics
// onto bias-pre-initialized out (waves tile 128x256 disjointly in-block).
// ---------------------------------------------------------------------------

typedef _Float16 f16x8 __attribute__((ext_vector_type(8)));
typedef float    f32x4 __attribute__((ext_vector_type(4)));

#define WS_WT_OFF  0            // WT2 : 8 MB, q-major fragment order (R12's)
#define WS_XF_OFF  8388608      // Xf  : 1 MB, x f16 seg-XOR
#define WS_X0_OFF  9437184      // X0T2: 1 MB, x0 f16 [mb64][row][f] swizzled
#define WS_NEEDED  10485760

__device__ __forceinline__ void gl_lds16(const void* g, void* l) {
  __builtin_amdgcn_global_load_lds(
      (const __attribute__((address_space(1))) void*)g,
      (__attribute__((address_space(3))) void*)l, 16, 0, 0);
}

// ------------------------------ prep kernel --------------------------------
// [0,524288): W f32->f16, q-major window order (same as R12):
//   ks=k8>>2 g=k8&3; sv=ks>>6 (k-slice 0..7); r=ks&63; f=r>>2; q=r&3;
//   WT2 f16 idx = ((oq*512 + sv*64 + q*16+f)*4 + g)*512 + (o&63)*8,  oq=o>>6.
// [524288,589824): x f32->f16 + 16B-seg XOR keyed row&7.
// [589824,655360): x0 f16 [mb64][row(64)][f(128)], 16B f-blocks XOR'd row&7.
// [655360,917504): out = bias (float4 groups).
__global__ __launch_bounds__(256) void prep_kernel(
    const float* __restrict__ x0, const float* __restrict__ x,
    const float* __restrict__ W, const float* __restrict__ bias,
    _Float16* __restrict__ WT2, _Float16* __restrict__ Xf,
    _Float16* __restrict__ X0T2, float* __restrict__ out)
{
  int i = blockIdx.x * 256 + threadIdx.x;
  if (i < 524288) {
    int o = i >> 11, k8 = i & 2047;
    const float* s = W + ((size_t)o << 14) + ((size_t)k8 << 3);
    f16x8 h;
#pragma unroll
    for (int e = 0; e < 8; ++e) h[e] = (_Float16)s[e];
    int ks = k8 >> 2, g = k8 & 3, oq = o >> 6, o6 = o & 63;
    int sv = ks >> 6, r = ks & 63, f = r >> 2, q = r & 3;
    *(f16x8*)(WT2 + ((size_t)((oq * 512 + sv * 64 + q * 16 + f) * 4 + g)) * 512 +
              o6 * 8) = h;
  } else if (i < 589824) {
    int j = i - 524288;
    int r = j >> 4, seg = j & 15;
    const float* s = x + r * 128 + seg * 8;
    f16x8 h;
#pragma unroll
    for (int e = 0; e < 8; ++e) h[e] = (_Float16)s[e];
    int segp = seg ^ (r & 7);
    *(f16x8*)(Xf + r * 128 + segp * 8) = h;
  } else if (i < 655360) {
    int j = i - 589824;                // (mb64, row, 8-f block)
    int mb = j >> 10, rem = j & 1023;
    int row = rem >> 4, jb = rem & 15;
    f16x8 h;
#pragma unroll
    for (int e = 0; e < 8; ++e)
      h[e] = (_Float16)x0[(size_t)(mb * 64 + row) * 128 + jb * 8 + e];
    *(f16x8*)(X0T2 + (size_t)mb * 8192 + row * 128 + (jb ^ (row & 7)) * 8) = h;
  } else {
    int j = i - 655360;                // float4 idx into out[4096][256]
    int c = (j * 4) & 255;
    ((float4*)out)[j] = *(const float4*)(bias + c);
  }
}

// ------------------------------ GEMM kernel --------------------------------
// smem: [0,32768) x_s [128r][128p] f16 swz; [32768,65536) x0t [128r][128f].
__global__ __launch_bounds__(512, 1) void gemm_kernel(
    const _Float16* __restrict__ WT2, const _Float16* __restrict__ Xf,
    const _Float16* __restrict__ X0T2, float* __restrict__ out)
{
  __shared__ __align__(16) char smem[65536];

  const int bid = blockIdx.x;
  const int mb  = bid >> 3;          // 0..31 : 128-row block
  const int sk  = bid & 7;           // 0..7  : k-slice (f sk*16..+15) -> XCD

  const int t   = threadIdx.x;
  const int l   = t & 63;
  const int wv  = t >> 6;
  const int wm  = wv >> 2;           // 0..1 : 64-row half
  const int wn  = wv & 3;            // 0..3 : 64-o quarter
  const int lr  = l & 15;
  const int lg  = l >> 4;
  const int swz = lr & 7;
  const int l16 = l * 16;

  // wave W stream base: o-quarter wn, k-slice sk (m-paired waves share it)
  const char* wsrc = (const char*)WT2 + ((size_t)(wn * 512 + sk * 64)) * 4096;

  // ---- prologue: x_s (32 KB) + x0t (32 KB) -> LDS (one-time) ----
  const char* xsb = (const char*)Xf + (size_t)mb * 32768;
#pragma unroll
  for (int i = 0; i < 4; ++i)
    gl_lds16(xsb + i * 8192 + t * 16, smem + i * 8192 + t * 16);
  const char* x0b = (const char*)X0T2 + (size_t)mb * 32768;
#pragma unroll
  for (int i = 0; i < 4; ++i)
    gl_lds16(x0b + i * 8192 + t * 16, smem + 32768 + i * 8192 + t * 16);
  __syncthreads();

  f32x4 acc[4][4] = {};
  f16x8 xa[4], x0v[4], bw0[4], bw1[4], bw2[4];

  const int xrb = (wm * 64 + lr) * 256;       // byte base of lane's x row
#pragma unroll
  for (int m = 0; m < 4; ++m)
    xa[m] = *(const f16x8*)(smem + xrb + m * 4096 + ((lg ^ swz) << 4));
#pragma unroll
  for (int m = 0; m < 4; ++m)
    x0v[m] = *(const f16x8*)(smem + 32768 + xrb + m * 4096 +
                             (((sk * 2) ^ swz) << 4));
  // prime: windows 0,1 (plain loads; compiler counts vmcnt)
#pragma unroll
  for (int i = 0; i < 4; ++i)
    bw0[i] = *(const f16x8*)(wsrc + 0 * 4096 + i * 256 + lg * 1024 + lr * 16);
#pragma unroll
  for (int i = 0; i < 4; ++i)
    bw1[i] = *(const f16x8*)(wsrc + 1 * 4096 + i * 256 + lg * 1024 + lr * 16);

  const int wofs = lg * 1024 + lr * 16;

  // STEP(WI, BR, BW_, STG): issue window WI+2 -> BW_; boundary xa/x0v
  // reloads (for WI+1); 16 MFMA from BR. No asm, no barriers.
#define STEP(WI, BR, BW_, STG) { \
    if (STG) { \
      _Pragma("unroll") \
      for (int i = 0; i < 4; ++i) \
        BW_[i] = *(const f16x8*)(wsrc + ((WI) + 2) * 4096 + i * 256 + wofs); \
    } \
    f16x8 av[4]; \
    _Pragma("unroll") \
    for (int m = 0; m < 4; ++m) \
      av[m] = xa[m] * x0v[m][(WI) & 7]; \
    if ((((WI) + 1) & 15) == 0 && (WI) < 63) { \
      _Pragma("unroll") \
      for (int m = 0; m < 4; ++m) \
        xa[m] = *(const f16x8*)(smem + xrb + m * 4096 + \
                 ((((((WI) + 1) >> 4) * 4 + lg) ^ swz) << 4)); \
    } \
    if ((((WI) + 1) & 7) == 0 && (WI) < 63) { \
      _Pragma("unroll") \
      for (int m = 0; m < 4; ++m) \
        x0v[m] = *(const f16x8*)(smem + 32768 + xrb + m * 4096 + \
                  (((sk * 2 + ((((WI) + 1) >> 3) & 1)) ^ swz) << 4)); \
    } \
    _Pragma("unroll") \
    for (int m = 0; m < 4; ++m) { \
      _Pragma("unroll") \
      for (int n = 0; n < 4; ++n) \
        acc[m][n] = __builtin_amdgcn_mfma_f32_16x16x32_f16( \
            av[m], BR[n], acc[m][n], 0, 0, 0); \
    } \
  }

#define S0(WI, STG) STEP(WI, bw0, bw2, STG)
#define S1(WI, STG) STEP(WI, bw1, bw0, STG)
#define S2(WI, STG) STEP(WI, bw2, bw1, STG)

  S0(0,1)  S1(1,1)  S2(2,1)  S0(3,1)  S1(4,1)  S2(5,1)
  S0(6,1)  S1(7,1)  S2(8,1)  S0(9,1)  S1(10,1) S2(11,1)
  S0(12,1) S1(13,1) S2(14,1) S0(15,1) S1(16,1) S2(17,1)
  S0(18,1) S1(19,1) S2(20,1) S0(21,1) S1(22,1) S2(23,1)
  S0(24,1) S1(25,1) S2(26,1) S0(27,1) S1(28,1) S2(29,1)
  S0(30,1) S1(31,1) S2(32,1) S0(33,1) S1(34,1) S2(35,1)
  S0(36,1) S1(37,1) S2(38,1) S0(39,1) S1(40,1) S2(41,1)
  S0(42,1) S1(43,1) S2(44,1) S0(45,1) S1(46,1) S2(47,1)
  S0(48,1) S1(49,1) S2(50,1) S0(51,1) S1(52,1) S2(53,1)
  S0(54,1) S1(55,1) S2(56,1) S0(57,1) S1(58,1) S2(59,1)
  S0(60,1) S1(61,1) S2(62,0) S0(63,0)

#undef S0
#undef S1
#undef S2
#undef STEP

  // ---- epilogue: split-K-8 accumulate (out pre-initialized to bias) ----
  // C/D layout: col = lane&15, row = (lane>>4)*4 + reg
  float* op = out + (size_t)(mb * 128 + wm * 64 + lg * 4) * 256 + wn * 64 + lr;
#pragma unroll
  for (int m = 0; m < 4; ++m)
#pragma unroll
    for (int n = 0; n < 4; ++n)
#pragma unroll
      for (int rr = 0; rr < 4; ++rr)
        unsafeAtomicAdd(op + (size_t)(m * 16 + rr) * 256 + n * 16,
                        acc[m][n][rr]);
}

// --------------------------- fallback (no ws) ------------------------------
__global__ __launch_bounds__(256) void naive_kernel(
    const float* __restrict__ x0, const float* __restrict__ x,
    const float* __restrict__ W, const float* __restrict__ bias,
    float* __restrict__ out)
{
  __shared__ float x0_s[16][128];
  __shared__ float x_s[16][128];
  const int tid = threadIdx.x;
  const int b0  = blockIdx.x * 16;
  for (int i = tid; i < 16 * 128; i += 256) {
    int bb = i >> 7, c = i & 127;
    x0_s[bb][c] = x0[(size_t)(b0 + bb) * 128 + c];
    x_s[bb][c]  = x[(size_t)(b0 + bb) * 128 + c];
  }
  __syncthreads();
  const int lane = tid & 63, wv = tid >> 6;
  for (int o = wv; o < 256; o += 4) {
    float acc[16];
#pragma unroll
    for (int bb = 0; bb < 16; ++bb) acc[bb] = 0.f;
    for (int it = 0; it < 256; ++it) {
      int k = it * 64 + lane;
      float wval = W[(size_t)o * 16384 + k];
      int f = k >> 7, p = k & 127;
#pragma unroll
      for (int bb = 0; bb < 16; ++bb)
        acc[bb] += wval * (x0_s[bb][f] * x_s[bb][p]);
    }
#pragma unroll
    for (int bb = 0; bb < 16; ++bb) {
      float v = acc[bb];
      for (int off = 32; off; off >>= 1) v += __shfl_down(v, off);
      if (lane == 0) out[(size_t)(b0 + bb) * 256 + o] = v + bias[o];
    }
  }
}

// ------------------------------- launcher ----------------------------------
extern "C" void kernel_launch(void* const* d_in, const int* in_sizes, int n_in,
                              void* d_out, int out_size, void* d_ws,
                              size_t ws_size, hipStream_t stream)
{
  const float* x0   = (const float*)d_in[0];
  const float* x    = (const float*)d_in[1];
  const float* W    = (const float*)d_in[2];
  const float* bias = (const float*)d_in[3];
  float* out = (float*)d_out;

  if (ws_size >= (size_t)WS_NEEDED) {
    _Float16* WT2  = (_Float16*)((char*)d_ws + WS_WT_OFF);
    _Float16* Xf   = (_Float16*)((char*)d_ws + WS_XF_OFF);
    _Float16* X0T2 = (_Float16*)((char*)d_ws + WS_X0_OFF);
    prep_kernel<<<3584, 256, 0, stream>>>(x0, x, W, bias, WT2, Xf, X0T2, out);
    gemm_kernel<<<256, 512, 0, stream>>>(WT2, Xf, X0T2, out);
  } else {
    naive_kernel<<<256, 256, 0, stream>>>(x0, x, W, bias, out);
  }
}